// Round 5
// baseline (944.479 us; speedup 1.0000x reference)
//
#include <hip/hip_runtime.h>
#include <math.h>

// NNUE forward, all f32. B=8192, N_IN=12288, H0=256, H1=H2=32.
// R5: branch-free bitmap producer/consumer.
//   Kernel A (scan): pure stream of white/black -> 4-bit-per-uint4 nonzero
//     bitmap (1 byte per 4 features). No atomics, no branches, no divides.
//   Kernel B (gather+MLP): per-sample block expands its bitmap row into an
//     LDS index list (LDS atomics), gathers ft_w^T columns, runs tail layers.
// Floor: streaming 805 MB of feature data (~128 us at 6.3 TB/s).

#define NIN   12288
#define NF4   3072   // NIN / 4 floats per float4
#define NDW   768    // bitmap dwords per sample row (NF4 bytes / 4)
#define FPT   12     // NF4 / 256 threads (fallback kernel)
#define H0    256
#define MAXF  192    // per-sample active-feature cap (mean ~31)

// ---------------------------------------------------------------- transpose
// ft_w (256 x 12288) -> ft_w_T (12288 x 256), f32, LDS-tiled.
__global__ __launch_bounds__(256) void transpose_ftw(const float* __restrict__ src,
                                                     float* __restrict__ dst) {
    __shared__ float tile[32][33];
    const int jb = blockIdx.x * 32;
    const int hb = blockIdx.y * 32;
    const int tx = threadIdx.x;
    const int ty = threadIdx.y;
#pragma unroll
    for (int r = 0; r < 32; r += 8)
        tile[ty + r][tx] = src[(size_t)(hb + ty + r) * NIN + jb + tx];
    __syncthreads();
#pragma unroll
    for (int r = 0; r < 32; r += 8)
        dst[(size_t)(jb + ty + r) * H0 + hb + tx] = tile[tx][ty + r];
}

// ---------------------------------------------------------------- kernel A
__device__ __forceinline__ unsigned char mask4(uint4 u) {
    return (unsigned char)((u.x ? 1u : 0u) | (u.y ? 2u : 0u) |
                           (u.z ? 4u : 0u) | (u.w ? 8u : 0u));
}

__global__ __launch_bounds__(256) void scan_kernel(const uint4* __restrict__ white,
                                                   const uint4* __restrict__ black,
                                                   unsigned char* __restrict__ wbm,
                                                   unsigned char* __restrict__ bbm,
                                                   int total)   // B * NF4 uint4 items
{
    const int stride = gridDim.x * 256;
    int i = blockIdx.x * 256 + threadIdx.x;
    for (; i + 3 * stride < total; i += 4 * stride) {
        const uint4 w0 = white[i];
        const uint4 w1 = white[i + stride];
        const uint4 w2 = white[i + 2 * stride];
        const uint4 w3 = white[i + 3 * stride];
        const uint4 b0 = black[i];
        const uint4 b1 = black[i + stride];
        const uint4 b2 = black[i + 2 * stride];
        const uint4 b3 = black[i + 3 * stride];
        wbm[i]              = mask4(w0);
        wbm[i + stride]     = mask4(w1);
        wbm[i + 2 * stride] = mask4(w2);
        wbm[i + 3 * stride] = mask4(w3);
        bbm[i]              = mask4(b0);
        bbm[i + stride]     = mask4(b1);
        bbm[i + 2 * stride] = mask4(b2);
        bbm[i + 3 * stride] = mask4(b3);
    }
    for (; i < total; i += stride) {
        wbm[i] = mask4(white[i]);
        bbm[i] = mask4(black[i]);
    }
}

// ---------------------------------------------------------------- kernel B
__global__ __launch_bounds__(256) void gather_kernel(
    const int* __restrict__ side,        // (B,)
    const float* __restrict__ ftw,       // (NIN,256) transposed
    const float* __restrict__ ft_b,      // (256,)
    const float* __restrict__ l1_w,      // (32,512)
    const float* __restrict__ l1_b,
    const float* __restrict__ l2_w,      // (32,32)
    const float* __restrict__ l2_b,
    const float* __restrict__ l3_w,      // (32,)
    const float* __restrict__ l3_b,      // (1,)
    const unsigned char* __restrict__ wbm,  // (B, NF4) bytes
    const unsigned char* __restrict__ bbm,
    float* __restrict__ out)             // (B,)
{
    __shared__ int w_list[MAXF];
    __shared__ int b_list[MAXF];
    __shared__ int w_cnt, b_cnt;
    __shared__ float sh_o0[512] __attribute__((aligned(16)));
    __shared__ float sh_o1[32];
    __shared__ float sh_o2[32];

    const int s   = blockIdx.x;
    const int tid = threadIdx.x;

    if (tid == 0) { w_cnt = 0; b_cnt = 0; }
    __syncthreads();

    // ---- expand bitmap row into LDS index lists (LDS atomics, ~62 total) ----
    const unsigned* wrow = (const unsigned*)(wbm + (size_t)s * NF4);
    const unsigned* brow = (const unsigned*)(bbm + (size_t)s * NF4);
#pragma unroll
    for (int q = 0; q < 3; ++q) {                 // NDW = 3 * 256
        const int d = q * 256 + tid;
        unsigned v = wrow[d];
        while (v) {
            const int bpos = __ffs(v) - 1;        // bit in dword; (bpos&7) < 4
            const int j = ((d * 4 + (bpos >> 3)) << 2) + (bpos & 7);
            const int p = atomicAdd(&w_cnt, 1);
            if (p < MAXF) w_list[p] = j;
            v &= v - 1;
        }
        unsigned vb = brow[d];
        while (vb) {
            const int bpos = __ffs(vb) - 1;
            const int j = ((d * 4 + (bpos >> 3)) << 2) + (bpos & 7);
            const int p = atomicAdd(&b_cnt, 1);
            if (p < MAXF) b_list[p] = j;
            vb &= vb - 1;
        }
    }
    __syncthreads();

    const int wn = min(w_cnt, MAXF);
    const int bn = min(b_cnt, MAXF);

    // ---- gather-sum ft_w^T columns; thread t owns hidden unit t; 8-wide ILP ----
    const float bias = ft_b[tid];
    const float* col = ftw + tid;
    float wacc = bias;
    float bacc = bias;
    {
        int k = 0;
        for (; k + 8 <= wn; k += 8) {
            const float f0 = col[(size_t)w_list[k]     * H0];
            const float f1 = col[(size_t)w_list[k + 1] * H0];
            const float f2 = col[(size_t)w_list[k + 2] * H0];
            const float f3 = col[(size_t)w_list[k + 3] * H0];
            const float f4 = col[(size_t)w_list[k + 4] * H0];
            const float f5 = col[(size_t)w_list[k + 5] * H0];
            const float f6 = col[(size_t)w_list[k + 6] * H0];
            const float f7 = col[(size_t)w_list[k + 7] * H0];
            wacc += ((f0 + f1) + (f2 + f3)) + ((f4 + f5) + (f6 + f7));
        }
        for (; k < wn; ++k) wacc += col[(size_t)w_list[k] * H0];
        k = 0;
        for (; k + 8 <= bn; k += 8) {
            const float f0 = col[(size_t)b_list[k]     * H0];
            const float f1 = col[(size_t)b_list[k + 1] * H0];
            const float f2 = col[(size_t)b_list[k + 2] * H0];
            const float f3 = col[(size_t)b_list[k + 3] * H0];
            const float f4 = col[(size_t)b_list[k + 4] * H0];
            const float f5 = col[(size_t)b_list[k + 5] * H0];
            const float f6 = col[(size_t)b_list[k + 6] * H0];
            const float f7 = col[(size_t)b_list[k + 7] * H0];
            bacc += ((f0 + f1) + (f2 + f3)) + ((f4 + f5) + (f6 + f7));
        }
        for (; k < bn; ++k) bacc += col[(size_t)b_list[k] * H0];
    }
    const float ow = fminf(fmaxf(wacc, 0.f), 1.f);
    const float ob = fminf(fmaxf(bacc, 0.f), 1.f);
    const bool sd = (side[s] != 0);
    sh_o0[tid]       = sd ? ow : ob;
    sh_o0[256 + tid] = sd ? ob : ow;
    __syncthreads();

    // ---- l1: (32,512); 8 threads/output, p-staggered (bank-conflict-free) ----
    {
        const int o = tid >> 3;
        const int p = tid & 7;
        const float4* wp = (const float4*)(l1_w + (o * 512 + p * 64));
        const float4* xp = (const float4*)(sh_o0 + p * 64);
        float sum = 0.f;
#pragma unroll
        for (int i = 0; i < 16; ++i) {
            const int v = (2 * p + i) & 15;
            float4 w4 = wp[v];
            float4 x4 = xp[v];
            sum += w4.x * x4.x + w4.y * x4.y + w4.z * x4.z + w4.w * x4.w;
        }
        sum += __shfl_down(sum, 4, 8);
        sum += __shfl_down(sum, 2, 8);
        sum += __shfl_down(sum, 1, 8);
        if (p == 0) sh_o1[o] = fminf(fmaxf(sum + l1_b[o], 0.f), 1.f);
    }
    __syncthreads();

    if (tid < 32) {
        float sum = 0.f;
#pragma unroll
        for (int k = 0; k < 32; ++k) sum += l2_w[tid * 32 + k] * sh_o1[k];
        sh_o2[tid] = fminf(fmaxf(sum + l2_b[tid], 0.f), 1.f);
    }
    __syncthreads();

    if (tid < 32) {
        float p = l3_w[tid] * sh_o2[tid];
        p += __shfl_down(p, 16, 32);
        p += __shfl_down(p, 8, 32);
        p += __shfl_down(p, 4, 32);
        p += __shfl_down(p, 2, 32);
        p += __shfl_down(p, 1, 32);
        if (tid == 0) {
            const float o3  = (p + l3_b[0]) * 300.0f;
            out[s] = 1.0f / (1.0f + expf(-o3 / 200.0f));
        }
    }
}

// ---------------------------------------------------------------- fallback (R3 monolith)
template <bool TRANSPOSED>
__global__ __launch_bounds__(256) void nnue_kernel(
    const float* __restrict__ white, const float* __restrict__ black,
    const int* __restrict__ side, const float* __restrict__ ftw,
    const float* __restrict__ ft_b, const float* __restrict__ l1_w,
    const float* __restrict__ l1_b, const float* __restrict__ l2_w,
    const float* __restrict__ l2_b, const float* __restrict__ l3_w,
    const float* __restrict__ l3_b, float* __restrict__ out)
{
    __shared__ int w_list[MAXF];
    __shared__ int b_list[MAXF];
    __shared__ int w_cnt, b_cnt;
    __shared__ float sh_o0[512] __attribute__((aligned(16)));
    __shared__ float sh_o1[32];
    __shared__ float sh_o2[32];
    const int s = blockIdx.x, tid = threadIdx.x;
    if (tid == 0) { w_cnt = 0; b_cnt = 0; }
    __syncthreads();
    const uint4* wrow = (const uint4*)(white + (size_t)s * NIN);
    const uint4* brow = (const uint4*)(black + (size_t)s * NIN);
#pragma unroll
    for (int i = 0; i < FPT; ++i) {
        const int v = i * 256 + tid;
        uint4 u = wrow[v];
        if (u.x | u.y | u.z | u.w) {
            if (u.x) { int p = atomicAdd(&w_cnt, 1); if (p < MAXF) w_list[p] = v * 4 + 0; }
            if (u.y) { int p = atomicAdd(&w_cnt, 1); if (p < MAXF) w_list[p] = v * 4 + 1; }
            if (u.z) { int p = atomicAdd(&w_cnt, 1); if (p < MAXF) w_list[p] = v * 4 + 2; }
            if (u.w) { int p = atomicAdd(&w_cnt, 1); if (p < MAXF) w_list[p] = v * 4 + 3; }
        }
        uint4 b = brow[v];
        if (b.x | b.y | b.z | b.w) {
            if (b.x) { int p = atomicAdd(&b_cnt, 1); if (p < MAXF) b_list[p] = v * 4 + 0; }
            if (b.y) { int p = atomicAdd(&b_cnt, 1); if (p < MAXF) b_list[p] = v * 4 + 1; }
            if (b.z) { int p = atomicAdd(&b_cnt, 1); if (p < MAXF) b_list[p] = v * 4 + 2; }
            if (b.w) { int p = atomicAdd(&b_cnt, 1); if (p < MAXF) b_list[p] = v * 4 + 3; }
        }
    }
    __syncthreads();
    const int wn = min(w_cnt, MAXF), bn = min(b_cnt, MAXF);
    const float bias = ft_b[tid];
    float wacc = bias, bacc = bias;
    for (int k = 0; k < wn; ++k) {
        const int j = w_list[k];
        wacc += TRANSPOSED ? ftw[(size_t)j * H0 + tid] : ftw[(size_t)tid * NIN + j];
    }
    for (int k = 0; k < bn; ++k) {
        const int j = b_list[k];
        bacc += TRANSPOSED ? ftw[(size_t)j * H0 + tid] : ftw[(size_t)tid * NIN + j];
    }
    const float ow = fminf(fmaxf(wacc, 0.f), 1.f);
    const float ob = fminf(fmaxf(bacc, 0.f), 1.f);
    const bool sd = (side[s] != 0);
    sh_o0[tid] = sd ? ow : ob;
    sh_o0[256 + tid] = sd ? ob : ow;
    __syncthreads();
    {
        const int o = tid >> 3, p = tid & 7;
        const float4* wp = (const float4*)(l1_w + (o * 512 + p * 64));
        const float4* xp = (const float4*)(sh_o0 + p * 64);
        float sum = 0.f;
#pragma unroll
        for (int i = 0; i < 16; ++i) {
            const int v = (2 * p + i) & 15;
            float4 w4 = wp[v]; float4 x4 = xp[v];
            sum += w4.x * x4.x + w4.y * x4.y + w4.z * x4.z + w4.w * x4.w;
        }
        sum += __shfl_down(sum, 4, 8);
        sum += __shfl_down(sum, 2, 8);
        sum += __shfl_down(sum, 1, 8);
        if (p == 0) sh_o1[o] = fminf(fmaxf(sum + l1_b[o], 0.f), 1.f);
    }
    __syncthreads();
    if (tid < 32) {
        float sum = 0.f;
#pragma unroll
        for (int k = 0; k < 32; ++k) sum += l2_w[tid * 32 + k] * sh_o1[k];
        sh_o2[tid] = fminf(fmaxf(sum + l2_b[tid], 0.f), 1.f);
    }
    __syncthreads();
    if (tid < 32) {
        float p = l3_w[tid] * sh_o2[tid];
        p += __shfl_down(p, 16, 32);
        p += __shfl_down(p, 8, 32);
        p += __shfl_down(p, 4, 32);
        p += __shfl_down(p, 2, 32);
        p += __shfl_down(p, 1, 32);
        if (tid == 0) {
            const float o3 = (p + l3_b[0]) * 300.0f;
            out[s] = 1.0f / (1.0f + expf(-o3 / 200.0f));
        }
    }
}

// ---------------------------------------------------------------- launch
extern "C" void kernel_launch(void* const* d_in, const int* in_sizes, int n_in,
                              void* d_out, int out_size, void* d_ws, size_t ws_size,
                              hipStream_t stream) {
    const float* white = (const float*)d_in[0];
    const float* black = (const float*)d_in[1];
    const int*   side  = (const int*)d_in[2];
    const float* ft_w  = (const float*)d_in[3];
    const float* ft_b  = (const float*)d_in[4];
    const float* l1_w  = (const float*)d_in[5];
    const float* l1_b  = (const float*)d_in[6];
    const float* l2_w  = (const float*)d_in[7];
    const float* l2_b  = (const float*)d_in[8];
    const float* l3_w  = (const float*)d_in[9];
    const float* l3_b  = (const float*)d_in[10];
    float*       out   = (float*)d_out;

    const int B = in_sizes[2];
    const size_t t_bytes  = (size_t)NIN * H0 * 4;          // ftw_t: 12.58 MB
    const size_t bm_bytes = (size_t)B * NF4;               // one bitmap: 25.2 MB
    const size_t need     = t_bytes + 2 * bm_bytes;        // ~63 MB

    if (ws_size >= need) {
        float*         ftw_t = (float*)d_ws;
        unsigned char* wbm   = (unsigned char*)d_ws + t_bytes;
        unsigned char* bbm   = wbm + bm_bytes;
        const int total = B * NF4;

        hipLaunchKernelGGL(transpose_ftw, dim3(NIN / 32, H0 / 32), dim3(32, 8), 0, stream,
                           ft_w, ftw_t);
        hipLaunchKernelGGL(scan_kernel, dim3(2048), dim3(256), 0, stream,
                           (const uint4*)white, (const uint4*)black, wbm, bbm, total);
        hipLaunchKernelGGL(gather_kernel, dim3(B), dim3(256), 0, stream,
                           side, ftw_t, ft_b, l1_w, l1_b, l2_w, l2_b, l3_w, l3_b,
                           wbm, bbm, out);
    } else if (ws_size >= t_bytes) {
        float* ftw_t = (float*)d_ws;
        hipLaunchKernelGGL(transpose_ftw, dim3(NIN / 32, H0 / 32), dim3(32, 8), 0, stream,
                           ft_w, ftw_t);
        hipLaunchKernelGGL((nnue_kernel<true>), dim3(B), dim3(256), 0, stream,
                           white, black, side, ftw_t, ft_b, l1_w, l1_b, l2_w, l2_b, l3_w, l3_b, out);
    } else {
        hipLaunchKernelGGL((nnue_kernel<false>), dim3(B), dim3(256), 0, stream,
                           white, black, side, ft_w, ft_b, l1_w, l1_b, l2_w, l2_b, l3_w, l3_b, out);
    }
}

// Round 6
// 883.838 us; speedup vs baseline: 1.0686x; 1.0686x over previous
//
#include <hip/hip_runtime.h>
#include <math.h>

// NNUE forward, all f32 in/out. B=8192, N_IN=12288, H0=256, H1=H2=32.
// R6: (1) scan = one-shot, statically unrolled 16-deep load batch (MLP fix,
//     VGPR-capped at 128 via __launch_bounds__(256,4));
//     (2) gather table in bf16 (half traffic), white/black split across
//     thread halves with packed 2-unit uint loads; f32 accumulation.
// Floor: streaming 805 MB of feature data (~128 us at 6.3 TB/s).

#define NIN   12288
#define NF4   3072   // NIN / 4 floats per float4
#define FPT   12     // fallback kernel
#define H0    256
#define MAXF  192    // per-sample active-feature cap (mean ~31)

__device__ __forceinline__ unsigned char mask4(uint4 u) {
    return (unsigned char)((u.x ? 1u : 0u) | (u.y ? 2u : 0u) |
                           (u.z ? 4u : 0u) | (u.w ? 8u : 0u));
}
__device__ __forceinline__ float bflo(unsigned u) { return __uint_as_float(u << 16); }
__device__ __forceinline__ float bfhi(unsigned u) { return __uint_as_float(u & 0xFFFF0000u); }

// ---------------------------------------------------------------- transpose
// ft_w (256 x 12288) f32 -> ft_w_T (12288 x 256) bf16 (RNE), LDS-tiled.
__global__ __launch_bounds__(256) void transpose_ftw_bf16(const float* __restrict__ src,
                                                          unsigned short* __restrict__ dst) {
    __shared__ float tile[32][33];
    const int jb = blockIdx.x * 32;
    const int hb = blockIdx.y * 32;
    const int tx = threadIdx.x;
    const int ty = threadIdx.y;
#pragma unroll
    for (int r = 0; r < 32; r += 8)
        tile[ty + r][tx] = src[(size_t)(hb + ty + r) * NIN + jb + tx];
    __syncthreads();
#pragma unroll
    for (int r = 0; r < 32; r += 8) {
        const unsigned u = __float_as_uint(tile[tx][ty + r]);
        const unsigned short h = (unsigned short)((u + 0x7FFFu + ((u >> 16) & 1u)) >> 16);
        dst[(size_t)(jb + ty + r) * H0 + hb + tx] = h;
    }
}

// ---------------------------------------------------------------- kernel A
__global__ __launch_bounds__(256, 4) void scan_kernel(const uint4* __restrict__ white,
                                                      const uint4* __restrict__ black,
                                                      unsigned char* __restrict__ wbm,
                                                      unsigned char* __restrict__ bbm,
                                                      int total)   // B * NF4 uint4 items
{
    const int i0 = blockIdx.x * 2048 + threadIdx.x;
    if (i0 + 7 * 256 < total) {
        uint4 w[8], b[8];
#pragma unroll
        for (int k = 0; k < 8; ++k) w[k] = white[i0 + k * 256];
#pragma unroll
        for (int k = 0; k < 8; ++k) b[k] = black[i0 + k * 256];
#pragma unroll
        for (int k = 0; k < 8; ++k) wbm[i0 + k * 256] = mask4(w[k]);
#pragma unroll
        for (int k = 0; k < 8; ++k) bbm[i0 + k * 256] = mask4(b[k]);
    } else {
#pragma unroll
        for (int k = 0; k < 8; ++k) {
            const int i = i0 + k * 256;
            if (i < total) { wbm[i] = mask4(white[i]); bbm[i] = mask4(black[i]); }
        }
    }
}

// ---------------------------------------------------------------- kernel B
__global__ __launch_bounds__(256) void gather_kernel(
    const int* __restrict__ side,           // (B,)
    const unsigned* __restrict__ tab,       // (NIN,128) uints = (NIN,256) bf16
    const float* __restrict__ ft_b,         // (256,)
    const float* __restrict__ l1_w,         // (32,512)
    const float* __restrict__ l1_b,
    const float* __restrict__ l2_w,         // (32,32)
    const float* __restrict__ l2_b,
    const float* __restrict__ l3_w,         // (32,)
    const float* __restrict__ l3_b,         // (1,)
    const unsigned char* __restrict__ wbm,  // (B, NF4) bytes
    const unsigned char* __restrict__ bbm,
    float* __restrict__ out)                // (B,)
{
    __shared__ int w_list[MAXF];
    __shared__ int b_list[MAXF];
    __shared__ int w_cnt, b_cnt;
    __shared__ float sh_o0[512] __attribute__((aligned(16)));
    __shared__ float sh_o1[32];
    __shared__ float sh_o2[32];

    const int s   = blockIdx.x;
    const int tid = threadIdx.x;

    if (tid == 0) { w_cnt = 0; b_cnt = 0; }
    __syncthreads();

    // ---- expand bitmap row into LDS index lists ----
    const unsigned* wrow = (const unsigned*)(wbm + (size_t)s * NF4);
    const unsigned* brow = (const unsigned*)(bbm + (size_t)s * NF4);
#pragma unroll
    for (int q = 0; q < 3; ++q) {                 // NF4/4 = 3 * 256 dwords
        const int d = q * 256 + tid;
        unsigned v = wrow[d];
        while (v) {
            const int bpos = __ffs(v) - 1;        // (bpos&7) < 4 always
            const int j = ((d * 4 + (bpos >> 3)) << 2) + (bpos & 7);
            const int p = atomicAdd(&w_cnt, 1);
            if (p < MAXF) w_list[p] = j;
            v &= v - 1;
        }
        unsigned vb = brow[d];
        while (vb) {
            const int bpos = __ffs(vb) - 1;
            const int j = ((d * 4 + (bpos >> 3)) << 2) + (bpos & 7);
            const int p = atomicAdd(&b_cnt, 1);
            if (p < MAXF) b_list[p] = j;
            vb &= vb - 1;
        }
    }
    __syncthreads();

    const int wn = min(w_cnt, MAXF);
    const int bn = min(b_cnt, MAXF);

    // ---- gather-sum bf16 columns; tid<128: white units (2h,2h+1); else black ----
    const int  h       = tid & 127;
    const bool isWhite = (tid < 128);
    const int* lst     = isWhite ? w_list : b_list;
    const int  n       = isWhite ? wn : bn;
    const unsigned* colp = tab + h;

    float accx = ft_b[2 * h];
    float accy = ft_b[2 * h + 1];
    {
        int k = 0;
        for (; k + 8 <= n; k += 8) {
            const unsigned u0 = colp[(size_t)lst[k]     * 128];
            const unsigned u1 = colp[(size_t)lst[k + 1] * 128];
            const unsigned u2 = colp[(size_t)lst[k + 2] * 128];
            const unsigned u3 = colp[(size_t)lst[k + 3] * 128];
            const unsigned u4 = colp[(size_t)lst[k + 4] * 128];
            const unsigned u5 = colp[(size_t)lst[k + 5] * 128];
            const unsigned u6 = colp[(size_t)lst[k + 6] * 128];
            const unsigned u7 = colp[(size_t)lst[k + 7] * 128];
            accx += ((bflo(u0) + bflo(u1)) + (bflo(u2) + bflo(u3))) +
                    ((bflo(u4) + bflo(u5)) + (bflo(u6) + bflo(u7)));
            accy += ((bfhi(u0) + bfhi(u1)) + (bfhi(u2) + bfhi(u3))) +
                    ((bfhi(u4) + bfhi(u5)) + (bfhi(u6) + bfhi(u7)));
        }
        for (; k < n; ++k) {
            const unsigned u = colp[(size_t)lst[k] * 128];
            accx += bflo(u);
            accy += bfhi(u);
        }
    }
    const float cx = fminf(fmaxf(accx, 0.f), 1.f);
    const float cy = fminf(fmaxf(accy, 0.f), 1.f);
    const bool sd = (side[s] != 0);
    const int base = (isWhite == sd) ? 0 : 256;   // white->first half iff side
    sh_o0[base + 2 * h]     = cx;
    sh_o0[base + 2 * h + 1] = cy;
    __syncthreads();

    // ---- l1: (32,512); 8 threads/output, p-staggered (bank-conflict-free) ----
    {
        const int o = tid >> 3;
        const int p = tid & 7;
        const float4* wp = (const float4*)(l1_w + (o * 512 + p * 64));
        const float4* xp = (const float4*)(sh_o0 + p * 64);
        float sum = 0.f;
#pragma unroll
        for (int i = 0; i < 16; ++i) {
            const int v = (2 * p + i) & 15;
            float4 w4 = wp[v];
            float4 x4 = xp[v];
            sum += w4.x * x4.x + w4.y * x4.y + w4.z * x4.z + w4.w * x4.w;
        }
        sum += __shfl_down(sum, 4, 8);
        sum += __shfl_down(sum, 2, 8);
        sum += __shfl_down(sum, 1, 8);
        if (p == 0) sh_o1[o] = fminf(fmaxf(sum + l1_b[o], 0.f), 1.f);
    }
    __syncthreads();

    if (tid < 32) {
        float sum = 0.f;
#pragma unroll
        for (int k = 0; k < 32; ++k) sum += l2_w[tid * 32 + k] * sh_o1[k];
        sh_o2[tid] = fminf(fmaxf(sum + l2_b[tid], 0.f), 1.f);
    }
    __syncthreads();

    if (tid < 32) {
        float p = l3_w[tid] * sh_o2[tid];
        p += __shfl_down(p, 16, 32);
        p += __shfl_down(p, 8, 32);
        p += __shfl_down(p, 4, 32);
        p += __shfl_down(p, 2, 32);
        p += __shfl_down(p, 1, 32);
        if (tid == 0) {
            const float o3 = (p + l3_b[0]) * 300.0f;
            out[s] = 1.0f / (1.0f + expf(-o3 / 200.0f));
        }
    }
}

// ---------------------------------------------------------------- fallback (monolith, f32, untransposed)
__global__ __launch_bounds__(256) void nnue_kernel(
    const float* __restrict__ white, const float* __restrict__ black,
    const int* __restrict__ side, const float* __restrict__ ftw,
    const float* __restrict__ ft_b, const float* __restrict__ l1_w,
    const float* __restrict__ l1_b, const float* __restrict__ l2_w,
    const float* __restrict__ l2_b, const float* __restrict__ l3_w,
    const float* __restrict__ l3_b, float* __restrict__ out)
{
    __shared__ int w_list[MAXF];
    __shared__ int b_list[MAXF];
    __shared__ int w_cnt, b_cnt;
    __shared__ float sh_o0[512] __attribute__((aligned(16)));
    __shared__ float sh_o1[32];
    __shared__ float sh_o2[32];
    const int s = blockIdx.x, tid = threadIdx.x;
    if (tid == 0) { w_cnt = 0; b_cnt = 0; }
    __syncthreads();
    const uint4* wrow = (const uint4*)(white + (size_t)s * NIN);
    const uint4* brow = (const uint4*)(black + (size_t)s * NIN);
#pragma unroll
    for (int i = 0; i < FPT; ++i) {
        const int v = i * 256 + tid;
        uint4 u = wrow[v];
        if (u.x | u.y | u.z | u.w) {
            if (u.x) { int p = atomicAdd(&w_cnt, 1); if (p < MAXF) w_list[p] = v * 4 + 0; }
            if (u.y) { int p = atomicAdd(&w_cnt, 1); if (p < MAXF) w_list[p] = v * 4 + 1; }
            if (u.z) { int p = atomicAdd(&w_cnt, 1); if (p < MAXF) w_list[p] = v * 4 + 2; }
            if (u.w) { int p = atomicAdd(&w_cnt, 1); if (p < MAXF) w_list[p] = v * 4 + 3; }
        }
        uint4 b = brow[v];
        if (b.x | b.y | b.z | b.w) {
            if (b.x) { int p = atomicAdd(&b_cnt, 1); if (p < MAXF) b_list[p] = v * 4 + 0; }
            if (b.y) { int p = atomicAdd(&b_cnt, 1); if (p < MAXF) b_list[p] = v * 4 + 1; }
            if (b.z) { int p = atomicAdd(&b_cnt, 1); if (p < MAXF) b_list[p] = v * 4 + 2; }
            if (b.w) { int p = atomicAdd(&b_cnt, 1); if (p < MAXF) b_list[p] = v * 4 + 3; }
        }
    }
    __syncthreads();
    const int wn = min(w_cnt, MAXF), bn = min(b_cnt, MAXF);
    const float bias = ft_b[tid];
    float wacc = bias, bacc = bias;
    for (int k = 0; k < wn; ++k) wacc += ftw[(size_t)tid * NIN + w_list[k]];
    for (int k = 0; k < bn; ++k) bacc += ftw[(size_t)tid * NIN + b_list[k]];
    const float ow = fminf(fmaxf(wacc, 0.f), 1.f);
    const float ob = fminf(fmaxf(bacc, 0.f), 1.f);
    const bool sd = (side[s] != 0);
    sh_o0[tid] = sd ? ow : ob;
    sh_o0[256 + tid] = sd ? ob : ow;
    __syncthreads();
    {
        const int o = tid >> 3, p = tid & 7;
        const float4* wp = (const float4*)(l1_w + (o * 512 + p * 64));
        const float4* xp = (const float4*)(sh_o0 + p * 64);
        float sum = 0.f;
#pragma unroll
        for (int i = 0; i < 16; ++i) {
            const int v = (2 * p + i) & 15;
            float4 w4 = wp[v]; float4 x4 = xp[v];
            sum += w4.x * x4.x + w4.y * x4.y + w4.z * x4.z + w4.w * x4.w;
        }
        sum += __shfl_down(sum, 4, 8);
        sum += __shfl_down(sum, 2, 8);
        sum += __shfl_down(sum, 1, 8);
        if (p == 0) sh_o1[o] = fminf(fmaxf(sum + l1_b[o], 0.f), 1.f);
    }
    __syncthreads();
    if (tid < 32) {
        float sum = 0.f;
#pragma unroll
        for (int k = 0; k < 32; ++k) sum += l2_w[tid * 32 + k] * sh_o1[k];
        sh_o2[tid] = fminf(fmaxf(sum + l2_b[tid], 0.f), 1.f);
    }
    __syncthreads();
    if (tid < 32) {
        float p = l3_w[tid] * sh_o2[tid];
        p += __shfl_down(p, 16, 32);
        p += __shfl_down(p, 8, 32);
        p += __shfl_down(p, 4, 32);
        p += __shfl_down(p, 2, 32);
        p += __shfl_down(p, 1, 32);
        if (tid == 0) {
            const float o3 = (p + l3_b[0]) * 300.0f;
            out[s] = 1.0f / (1.0f + expf(-o3 / 200.0f));
        }
    }
}

// ---------------------------------------------------------------- launch
extern "C" void kernel_launch(void* const* d_in, const int* in_sizes, int n_in,
                              void* d_out, int out_size, void* d_ws, size_t ws_size,
                              hipStream_t stream) {
    const float* white = (const float*)d_in[0];
    const float* black = (const float*)d_in[1];
    const int*   side  = (const int*)d_in[2];
    const float* ft_w  = (const float*)d_in[3];
    const float* ft_b  = (const float*)d_in[4];
    const float* l1_w  = (const float*)d_in[5];
    const float* l1_b  = (const float*)d_in[6];
    const float* l2_w  = (const float*)d_in[7];
    const float* l2_b  = (const float*)d_in[8];
    const float* l3_w  = (const float*)d_in[9];
    const float* l3_b  = (const float*)d_in[10];
    float*       out   = (float*)d_out;

    const int B = in_sizes[2];
    const size_t t_bytes  = (size_t)NIN * H0 * 2;          // bf16 ftw_t: 6.29 MB
    const size_t bm_bytes = (size_t)B * NF4;               // one bitmap: 25.2 MB
    const size_t need     = t_bytes + 2 * bm_bytes;        // ~57 MB

    if (ws_size >= need) {
        unsigned short* ftw_t = (unsigned short*)d_ws;
        unsigned char*  wbm   = (unsigned char*)d_ws + t_bytes;
        unsigned char*  bbm   = wbm + bm_bytes;
        const int total = B * NF4;

        hipLaunchKernelGGL(transpose_ftw_bf16, dim3(NIN / 32, H0 / 32), dim3(32, 8), 0, stream,
                           ft_w, ftw_t);
        hipLaunchKernelGGL(scan_kernel, dim3((total + 2047) / 2048), dim3(256), 0, stream,
                           (const uint4*)white, (const uint4*)black, wbm, bbm, total);
        hipLaunchKernelGGL(gather_kernel, dim3(B), dim3(256), 0, stream,
                           side, (const unsigned*)ftw_t, ft_b, l1_w, l1_b, l2_w, l2_b,
                           l3_w, l3_b, wbm, bbm, out);
    } else {
        hipLaunchKernelGGL(nnue_kernel, dim3(B), dim3(256), 0, stream,
                           white, black, side, ft_w, ft_b, l1_w, l1_b, l2_w, l2_b,
                           l3_w, l3_b, out);
    }
}

// Round 7
// 877.341 us; speedup vs baseline: 1.0765x; 1.0074x over previous
//
#include <hip/hip_runtime.h>
#include <math.h>

// NNUE forward, all f32 in/out. B=8192, N_IN=12288, H0=256, H1=H2=32.
// R7: scan via __builtin_amdgcn_global_load_lds (async DMA to LDS, 8 x 1KB in
//     flight per wave, wave-private regions, no __syncthreads) + dword-packed
//     bitmap stores via LDS repack. Gather (bf16 table, split halves) kept
//     from R6 (verified absmax 3.9e-3).
// Floor: streaming 805 MB of feature data (~128 us at 6.3 TB/s; ~half L3-hot).

#define NIN   12288
#define NF4   3072   // NIN / 4 floats per float4
#define FPT   12     // fallback kernel
#define H0    256
#define MAXF  192    // per-sample active-feature cap (mean ~31)

__device__ __forceinline__ unsigned char mask4(uint4 u) {
    return (unsigned char)((u.x ? 1u : 0u) | (u.y ? 2u : 0u) |
                           (u.z ? 4u : 0u) | (u.w ? 8u : 0u));
}
__device__ __forceinline__ float bflo(unsigned u) { return __uint_as_float(u << 16); }
__device__ __forceinline__ float bfhi(unsigned u) { return __uint_as_float(u & 0xFFFF0000u); }

// ---------------------------------------------------------------- transpose
// ft_w (256 x 12288) f32 -> ft_w_T (12288 x 256) bf16 (RNE), LDS-tiled.
__global__ __launch_bounds__(256) void transpose_ftw_bf16(const float* __restrict__ src,
                                                          unsigned short* __restrict__ dst) {
    __shared__ float tile[32][33];
    const int jb = blockIdx.x * 32;
    const int hb = blockIdx.y * 32;
    const int tx = threadIdx.x;
    const int ty = threadIdx.y;
#pragma unroll
    for (int r = 0; r < 32; r += 8)
        tile[ty + r][tx] = src[(size_t)(hb + ty + r) * NIN + jb + tx];
    __syncthreads();
#pragma unroll
    for (int r = 0; r < 32; r += 8) {
        const unsigned u = __float_as_uint(tile[tx][ty + r]);
        const unsigned short h = (unsigned short)((u + 0x7FFFu + ((u >> 16) & 1u)) >> 16);
        dst[(size_t)(jb + ty + r) * H0 + hb + tx] = h;
    }
}

// ---------------------------------------------------------------- kernel A
// Each block covers 1024 white + 1024 black uint4 (32 KB staged in LDS).
// Wave w stages its 256-uint4 quarter per side via async global->LDS DMA
// (8 x 1KB in flight), waits vmcnt(0), computes masks, repacks to dwords in
// a small LDS scratch, stores 256 B per wave per side coalesced.
// Bitmap byte i == mask of uint4 i (same mapping as R6; gather unchanged).
__global__ __launch_bounds__(256) void scan_kernel(const uint4* __restrict__ white,
                                                   const uint4* __restrict__ black,
                                                   unsigned* __restrict__ wbm32,
                                                   unsigned* __restrict__ bbm32)
{
    __shared__ uint4 stage[2048];                    // 32 KB: white [0,1024), black [1024,2048)
    __shared__ unsigned char scratch[2][1024];       // 2 KB mask repack

    const int tid  = threadIdx.x;
    const int wv   = tid >> 6;                       // wave 0..3
    const int lane = tid & 63;
    const size_t base = (size_t)blockIdx.x * 1024;   // uint4 index base (per side)

    const uint4* wsrc = white + base + wv * 256;     // + k*64 + lane
    const uint4* bsrc = black + base + wv * 256;
    uint4* wdst = stage + wv * 256;
    uint4* bdst = stage + 1024 + wv * 256;

#if __has_builtin(__builtin_amdgcn_global_load_lds)
#pragma unroll
    for (int k = 0; k < 4; ++k)
        __builtin_amdgcn_global_load_lds(
            (const __attribute__((address_space(1))) void*)(wsrc + k * 64 + lane),
            (__attribute__((address_space(3))) void*)(wdst + k * 64), 16, 0, 0);
#pragma unroll
    for (int k = 0; k < 4; ++k)
        __builtin_amdgcn_global_load_lds(
            (const __attribute__((address_space(1))) void*)(bsrc + k * 64 + lane),
            (__attribute__((address_space(3))) void*)(bdst + k * 64), 16, 0, 0);
    asm volatile("s_waitcnt vmcnt(0)" ::: "memory");
#else
#pragma unroll
    for (int k = 0; k < 4; ++k) wdst[k * 64 + lane] = wsrc[k * 64 + lane];
#pragma unroll
    for (int k = 0; k < 4; ++k) bdst[k * 64 + lane] = bsrc[k * 64 + lane];
#endif

    // consume own staged slots; write mask bytes to scratch (wave-private)
#pragma unroll
    for (int k = 0; k < 4; ++k) {
        scratch[0][wv * 256 + k * 64 + lane] = mask4(wdst[k * 64 + lane]);
        scratch[1][wv * 256 + k * 64 + lane] = mask4(bdst[k * 64 + lane]);
    }
    // repack: lane reads one dword (4 masks) and stores coalesced
    const unsigned wd = *(const unsigned*)&scratch[0][wv * 256 + lane * 4];
    const unsigned bd = *(const unsigned*)&scratch[1][wv * 256 + lane * 4];
    wbm32[(size_t)blockIdx.x * 256 + wv * 64 + lane] = wd;
    bbm32[(size_t)blockIdx.x * 256 + wv * 64 + lane] = bd;
}

// ---------------------------------------------------------------- kernel B
__global__ __launch_bounds__(256) void gather_kernel(
    const int* __restrict__ side,           // (B,)
    const unsigned* __restrict__ tab,       // (NIN,128) uints = (NIN,256) bf16
    const float* __restrict__ ft_b,         // (256,)
    const float* __restrict__ l1_w,         // (32,512)
    const float* __restrict__ l1_b,
    const float* __restrict__ l2_w,         // (32,32)
    const float* __restrict__ l2_b,
    const float* __restrict__ l3_w,         // (32,)
    const float* __restrict__ l3_b,         // (1,)
    const unsigned char* __restrict__ wbm,  // (B, NF4) bytes
    const unsigned char* __restrict__ bbm,
    float* __restrict__ out)                // (B,)
{
    __shared__ int w_list[MAXF];
    __shared__ int b_list[MAXF];
    __shared__ int w_cnt, b_cnt;
    __shared__ float sh_o0[512] __attribute__((aligned(16)));
    __shared__ float sh_o1[32];
    __shared__ float sh_o2[32];

    const int s   = blockIdx.x;
    const int tid = threadIdx.x;

    if (tid == 0) { w_cnt = 0; b_cnt = 0; }
    __syncthreads();

    // ---- expand bitmap row into LDS index lists ----
    const unsigned* wrow = (const unsigned*)(wbm + (size_t)s * NF4);
    const unsigned* brow = (const unsigned*)(bbm + (size_t)s * NF4);
#pragma unroll
    for (int q = 0; q < 3; ++q) {                 // NF4/4 = 3 * 256 dwords
        const int d = q * 256 + tid;
        unsigned v = wrow[d];
        while (v) {
            const int bpos = __ffs(v) - 1;        // (bpos&7) < 4 always
            const int j = ((d * 4 + (bpos >> 3)) << 2) + (bpos & 7);
            const int p = atomicAdd(&w_cnt, 1);
            if (p < MAXF) w_list[p] = j;
            v &= v - 1;
        }
        unsigned vb = brow[d];
        while (vb) {
            const int bpos = __ffs(vb) - 1;
            const int j = ((d * 4 + (bpos >> 3)) << 2) + (bpos & 7);
            const int p = atomicAdd(&b_cnt, 1);
            if (p < MAXF) b_list[p] = j;
            vb &= vb - 1;
        }
    }
    __syncthreads();

    const int wn = min(w_cnt, MAXF);
    const int bn = min(b_cnt, MAXF);

    // ---- gather-sum bf16 columns; tid<128: white units (2h,2h+1); else black ----
    const int  h       = tid & 127;
    const bool isWhite = (tid < 128);
    const int* lst     = isWhite ? w_list : b_list;
    const int  n       = isWhite ? wn : bn;
    const unsigned* colp = tab + h;

    float accx = ft_b[2 * h];
    float accy = ft_b[2 * h + 1];
    {
        int k = 0;
        for (; k + 8 <= n; k += 8) {
            const unsigned u0 = colp[(size_t)lst[k]     * 128];
            const unsigned u1 = colp[(size_t)lst[k + 1] * 128];
            const unsigned u2 = colp[(size_t)lst[k + 2] * 128];
            const unsigned u3 = colp[(size_t)lst[k + 3] * 128];
            const unsigned u4 = colp[(size_t)lst[k + 4] * 128];
            const unsigned u5 = colp[(size_t)lst[k + 5] * 128];
            const unsigned u6 = colp[(size_t)lst[k + 6] * 128];
            const unsigned u7 = colp[(size_t)lst[k + 7] * 128];
            accx += ((bflo(u0) + bflo(u1)) + (bflo(u2) + bflo(u3))) +
                    ((bflo(u4) + bflo(u5)) + (bflo(u6) + bflo(u7)));
            accy += ((bfhi(u0) + bfhi(u1)) + (bfhi(u2) + bfhi(u3))) +
                    ((bfhi(u4) + bfhi(u5)) + (bfhi(u6) + bfhi(u7)));
        }
        for (; k < n; ++k) {
            const unsigned u = colp[(size_t)lst[k] * 128];
            accx += bflo(u);
            accy += bfhi(u);
        }
    }
    const float cx = fminf(fmaxf(accx, 0.f), 1.f);
    const float cy = fminf(fmaxf(accy, 0.f), 1.f);
    const bool sd = (side[s] != 0);
    const int base = (isWhite == sd) ? 0 : 256;
    sh_o0[base + 2 * h]     = cx;
    sh_o0[base + 2 * h + 1] = cy;
    __syncthreads();

    // ---- l1: (32,512); 8 threads/output, p-staggered (bank-conflict-free) ----
    {
        const int o = tid >> 3;
        const int p = tid & 7;
        const float4* wp = (const float4*)(l1_w + (o * 512 + p * 64));
        const float4* xp = (const float4*)(sh_o0 + p * 64);
        float sum = 0.f;
#pragma unroll
        for (int i = 0; i < 16; ++i) {
            const int v = (2 * p + i) & 15;
            float4 w4 = wp[v];
            float4 x4 = xp[v];
            sum += w4.x * x4.x + w4.y * x4.y + w4.z * x4.z + w4.w * x4.w;
        }
        sum += __shfl_down(sum, 4, 8);
        sum += __shfl_down(sum, 2, 8);
        sum += __shfl_down(sum, 1, 8);
        if (p == 0) sh_o1[o] = fminf(fmaxf(sum + l1_b[o], 0.f), 1.f);
    }
    __syncthreads();

    if (tid < 32) {
        float sum = 0.f;
#pragma unroll
        for (int k = 0; k < 32; ++k) sum += l2_w[tid * 32 + k] * sh_o1[k];
        sh_o2[tid] = fminf(fmaxf(sum + l2_b[tid], 0.f), 1.f);
    }
    __syncthreads();

    if (tid < 32) {
        float p = l3_w[tid] * sh_o2[tid];
        p += __shfl_down(p, 16, 32);
        p += __shfl_down(p, 8, 32);
        p += __shfl_down(p, 4, 32);
        p += __shfl_down(p, 2, 32);
        p += __shfl_down(p, 1, 32);
        if (tid == 0) {
            const float o3 = (p + l3_b[0]) * 300.0f;
            out[s] = 1.0f / (1.0f + expf(-o3 / 200.0f));
        }
    }
}

// ---------------------------------------------------------------- fallback (monolith, f32, untransposed)
__global__ __launch_bounds__(256) void nnue_kernel(
    const float* __restrict__ white, const float* __restrict__ black,
    const int* __restrict__ side, const float* __restrict__ ftw,
    const float* __restrict__ ft_b, const float* __restrict__ l1_w,
    const float* __restrict__ l1_b, const float* __restrict__ l2_w,
    const float* __restrict__ l2_b, const float* __restrict__ l3_w,
    const float* __restrict__ l3_b, float* __restrict__ out)
{
    __shared__ int w_list[MAXF];
    __shared__ int b_list[MAXF];
    __shared__ int w_cnt, b_cnt;
    __shared__ float sh_o0[512] __attribute__((aligned(16)));
    __shared__ float sh_o1[32];
    __shared__ float sh_o2[32];
    const int s = blockIdx.x, tid = threadIdx.x;
    if (tid == 0) { w_cnt = 0; b_cnt = 0; }
    __syncthreads();
    const uint4* wrow = (const uint4*)(white + (size_t)s * NIN);
    const uint4* brow = (const uint4*)(black + (size_t)s * NIN);
#pragma unroll
    for (int i = 0; i < FPT; ++i) {
        const int v = i * 256 + tid;
        uint4 u = wrow[v];
        if (u.x | u.y | u.z | u.w) {
            if (u.x) { int p = atomicAdd(&w_cnt, 1); if (p < MAXF) w_list[p] = v * 4 + 0; }
            if (u.y) { int p = atomicAdd(&w_cnt, 1); if (p < MAXF) w_list[p] = v * 4 + 1; }
            if (u.z) { int p = atomicAdd(&w_cnt, 1); if (p < MAXF) w_list[p] = v * 4 + 2; }
            if (u.w) { int p = atomicAdd(&w_cnt, 1); if (p < MAXF) w_list[p] = v * 4 + 3; }
        }
        uint4 b = brow[v];
        if (b.x | b.y | b.z | b.w) {
            if (b.x) { int p = atomicAdd(&b_cnt, 1); if (p < MAXF) b_list[p] = v * 4 + 0; }
            if (b.y) { int p = atomicAdd(&b_cnt, 1); if (p < MAXF) b_list[p] = v * 4 + 1; }
            if (b.z) { int p = atomicAdd(&b_cnt, 1); if (p < MAXF) b_list[p] = v * 4 + 2; }
            if (b.w) { int p = atomicAdd(&b_cnt, 1); if (p < MAXF) b_list[p] = v * 4 + 3; }
        }
    }
    __syncthreads();
    const int wn = min(w_cnt, MAXF), bn = min(b_cnt, MAXF);
    const float bias = ft_b[tid];
    float wacc = bias, bacc = bias;
    for (int k = 0; k < wn; ++k) wacc += ftw[(size_t)tid * NIN + w_list[k]];
    for (int k = 0; k < bn; ++k) bacc += ftw[(size_t)tid * NIN + b_list[k]];
    const float ow = fminf(fmaxf(wacc, 0.f), 1.f);
    const float ob = fminf(fmaxf(bacc, 0.f), 1.f);
    const bool sd = (side[s] != 0);
    sh_o0[tid] = sd ? ow : ob;
    sh_o0[256 + tid] = sd ? ob : ow;
    __syncthreads();
    {
        const int o = tid >> 3, p = tid & 7;
        const float4* wp = (const float4*)(l1_w + (o * 512 + p * 64));
        const float4* xp = (const float4*)(sh_o0 + p * 64);
        float sum = 0.f;
#pragma unroll
        for (int i = 0; i < 16; ++i) {
            const int v = (2 * p + i) & 15;
            float4 w4 = wp[v]; float4 x4 = xp[v];
            sum += w4.x * x4.x + w4.y * x4.y + w4.z * x4.z + w4.w * x4.w;
        }
        sum += __shfl_down(sum, 4, 8);
        sum += __shfl_down(sum, 2, 8);
        sum += __shfl_down(sum, 1, 8);
        if (p == 0) sh_o1[o] = fminf(fmaxf(sum + l1_b[o], 0.f), 1.f);
    }
    __syncthreads();
    if (tid < 32) {
        float sum = 0.f;
#pragma unroll
        for (int k = 0; k < 32; ++k) sum += l2_w[tid * 32 + k] * sh_o1[k];
        sh_o2[tid] = fminf(fmaxf(sum + l2_b[tid], 0.f), 1.f);
    }
    __syncthreads();
    if (tid < 32) {
        float p = l3_w[tid] * sh_o2[tid];
        p += __shfl_down(p, 16, 32);
        p += __shfl_down(p, 8, 32);
        p += __shfl_down(p, 4, 32);
        p += __shfl_down(p, 2, 32);
        p += __shfl_down(p, 1, 32);
        if (tid == 0) {
            const float o3 = (p + l3_b[0]) * 300.0f;
            out[s] = 1.0f / (1.0f + expf(-o3 / 200.0f));
        }
    }
}

// ---------------------------------------------------------------- launch
extern "C" void kernel_launch(void* const* d_in, const int* in_sizes, int n_in,
                              void* d_out, int out_size, void* d_ws, size_t ws_size,
                              hipStream_t stream) {
    const float* white = (const float*)d_in[0];
    const float* black = (const float*)d_in[1];
    const int*   side  = (const int*)d_in[2];
    const float* ft_w  = (const float*)d_in[3];
    const float* ft_b  = (const float*)d_in[4];
    const float* l1_w  = (const float*)d_in[5];
    const float* l1_b  = (const float*)d_in[6];
    const float* l2_w  = (const float*)d_in[7];
    const float* l2_b  = (const float*)d_in[8];
    const float* l3_w  = (const float*)d_in[9];
    const float* l3_b  = (const float*)d_in[10];
    float*       out   = (float*)d_out;

    const int B = in_sizes[2];
    const size_t t_bytes  = (size_t)NIN * H0 * 2;          // bf16 ftw_t: 6.29 MB
    const size_t bm_bytes = (size_t)B * NF4;               // one bitmap: 25.2 MB
    const size_t need     = t_bytes + 2 * bm_bytes;        // ~57 MB

    if (ws_size >= need) {
        unsigned short* ftw_t = (unsigned short*)d_ws;
        unsigned char*  wbm   = (unsigned char*)d_ws + t_bytes;
        unsigned char*  bbm   = wbm + bm_bytes;
        const int total_u4 = B * NF4;                      // 25,165,824
        const int blocks   = total_u4 / 1024;              // 24576, exact

        hipLaunchKernelGGL(transpose_ftw_bf16, dim3(NIN / 32, H0 / 32), dim3(32, 8), 0, stream,
                           ft_w, ftw_t);
        hipLaunchKernelGGL(scan_kernel, dim3(blocks), dim3(256), 0, stream,
                           (const uint4*)white, (const uint4*)black,
                           (unsigned*)wbm, (unsigned*)bbm);
        hipLaunchKernelGGL(gather_kernel, dim3(B), dim3(256), 0, stream,
                           side, (const unsigned*)ftw_t, ft_b, l1_w, l1_b, l2_w, l2_b,
                           l3_w, l3_b, wbm, bbm, out);
    } else {
        hipLaunchKernelGGL(nnue_kernel, dim3(B), dim3(256), 0, stream,
                           white, black, side, ft_w, ft_b, l1_w, l1_b, l2_w, l2_b,
                           l3_w, l3_b, out);
    }
}

// Round 8
// 795.232 us; speedup vs baseline: 1.1877x; 1.1033x over previous
//
#include <hip/hip_runtime.h>
#include <math.h>

// NNUE forward, all f32 in/out. B=8192, N_IN=12288, H0=256, H1=H2=32.
// R8: back to the monolith (R3 structure, 270 us) — the producer/consumer
//     split serialized scan(250)+gather(70); in one kernel the gather/MLP
//     (L2/L3 pipes) overlaps the HBM read stream across staggered blocks.
//     Grafted improvements: bf16 transposed table + split-half gather
//     (tid<128 white / >=128 black, packed 2-unit loads; absmax 3.9e-3
//     verified in R6/R7) and p-staggered conflict-free l1.
// Measured machine limits: streaming READ ~3 TB/s (writes 6.5 TB/s) ->
//     805 MB feature stream floor ~250 us. Harness fixed overhead ~550 us.

#define NIN   12288
#define NF4   3072   // NIN / 4 floats per float4
#define H0    256
#define MAXF  192    // per-sample active-feature cap (mean ~31)

__device__ __forceinline__ float bflo(unsigned u) { return __uint_as_float(u << 16); }
__device__ __forceinline__ float bfhi(unsigned u) { return __uint_as_float(u & 0xFFFF0000u); }

// ---------------------------------------------------------------- transpose
// ft_w (256 x 12288) f32 -> ft_w_T (12288 x 256) bf16 (RNE), LDS-tiled.
__global__ __launch_bounds__(256) void transpose_ftw_bf16(const float* __restrict__ src,
                                                          unsigned short* __restrict__ dst) {
    __shared__ float tile[32][33];
    const int jb = blockIdx.x * 32;
    const int hb = blockIdx.y * 32;
    const int tx = threadIdx.x;
    const int ty = threadIdx.y;
#pragma unroll
    for (int r = 0; r < 32; r += 8)
        tile[ty + r][tx] = src[(size_t)(hb + ty + r) * NIN + jb + tx];
    __syncthreads();
#pragma unroll
    for (int r = 0; r < 32; r += 8) {
        const unsigned u = __float_as_uint(tile[tx][ty + r]);
        const unsigned short h = (unsigned short)((u + 0x7FFFu + ((u >> 16) & 1u)) >> 16);
        dst[(size_t)(jb + ty + r) * H0 + hb + tx] = h;
    }
}

// ---------------------------------------------------------------- monolith
__global__ __launch_bounds__(256) void nnue_mono(
    const float* __restrict__ white,        // (B, NIN)
    const float* __restrict__ black,
    const int* __restrict__ side,           // (B,)
    const unsigned* __restrict__ tab,       // (NIN,128) uints = (NIN,256) bf16
    const float* __restrict__ ft_b,         // (256,)
    const float* __restrict__ l1_w,         // (32,512)
    const float* __restrict__ l1_b,
    const float* __restrict__ l2_w,         // (32,32)
    const float* __restrict__ l2_b,
    const float* __restrict__ l3_w,         // (32,)
    const float* __restrict__ l3_b,         // (1,)
    float* __restrict__ out)                // (B,)
{
    __shared__ int w_list[MAXF];
    __shared__ int b_list[MAXF];
    __shared__ int w_cnt, b_cnt;
    __shared__ float sh_o0[512] __attribute__((aligned(16)));
    __shared__ float sh_o1[32];
    __shared__ float sh_o2[32];

    const int s   = blockIdx.x;
    const int tid = threadIdx.x;

    if (tid == 0) { w_cnt = 0; b_cnt = 0; }
    __syncthreads();

    // ---- Phase 1: stream both feature rows (24 uint4/thread), collect ----
    // 4-deep batched loads per side per iteration (keeps several loads in
    // flight without blowing VGPR budget; values are exactly 0.0f/1.0f).
    const uint4* wrow = (const uint4*)(white + (size_t)s * NIN);
    const uint4* brow = (const uint4*)(black + (size_t)s * NIN);
#pragma unroll
    for (int i = 0; i < 3; ++i) {
        uint4 w4[4], b4[4];
#pragma unroll
        for (int k = 0; k < 4; ++k) w4[k] = wrow[(i * 4 + k) * 256 + tid];
#pragma unroll
        for (int k = 0; k < 4; ++k) b4[k] = brow[(i * 4 + k) * 256 + tid];
#pragma unroll
        for (int k = 0; k < 4; ++k) {
            const int v = (i * 4 + k) * 256 + tid;
            const uint4 u = w4[k];
            if (u.x | u.y | u.z | u.w) {
                if (u.x) { int p = atomicAdd(&w_cnt, 1); if (p < MAXF) w_list[p] = v * 4 + 0; }
                if (u.y) { int p = atomicAdd(&w_cnt, 1); if (p < MAXF) w_list[p] = v * 4 + 1; }
                if (u.z) { int p = atomicAdd(&w_cnt, 1); if (p < MAXF) w_list[p] = v * 4 + 2; }
                if (u.w) { int p = atomicAdd(&w_cnt, 1); if (p < MAXF) w_list[p] = v * 4 + 3; }
            }
            const uint4 b = b4[k];
            if (b.x | b.y | b.z | b.w) {
                if (b.x) { int p = atomicAdd(&b_cnt, 1); if (p < MAXF) b_list[p] = v * 4 + 0; }
                if (b.y) { int p = atomicAdd(&b_cnt, 1); if (p < MAXF) b_list[p] = v * 4 + 1; }
                if (b.z) { int p = atomicAdd(&b_cnt, 1); if (p < MAXF) b_list[p] = v * 4 + 2; }
                if (b.w) { int p = atomicAdd(&b_cnt, 1); if (p < MAXF) b_list[p] = v * 4 + 3; }
            }
        }
    }
    __syncthreads();

    const int wn = min(w_cnt, MAXF);
    const int bn = min(b_cnt, MAXF);

    // ---- Phase 2: bf16 gather; tid<128: white units (2h,2h+1); else black ----
    const int  h       = tid & 127;
    const bool isWhite = (tid < 128);
    const int* lst     = isWhite ? w_list : b_list;
    const int  n       = isWhite ? wn : bn;
    const unsigned* colp = tab + h;

    float accx = ft_b[2 * h];
    float accy = ft_b[2 * h + 1];
    {
        int k = 0;
        for (; k + 8 <= n; k += 8) {
            const unsigned u0 = colp[(size_t)lst[k]     * 128];
            const unsigned u1 = colp[(size_t)lst[k + 1] * 128];
            const unsigned u2 = colp[(size_t)lst[k + 2] * 128];
            const unsigned u3 = colp[(size_t)lst[k + 3] * 128];
            const unsigned u4 = colp[(size_t)lst[k + 4] * 128];
            const unsigned u5 = colp[(size_t)lst[k + 5] * 128];
            const unsigned u6 = colp[(size_t)lst[k + 6] * 128];
            const unsigned u7 = colp[(size_t)lst[k + 7] * 128];
            accx += ((bflo(u0) + bflo(u1)) + (bflo(u2) + bflo(u3))) +
                    ((bflo(u4) + bflo(u5)) + (bflo(u6) + bflo(u7)));
            accy += ((bfhi(u0) + bfhi(u1)) + (bfhi(u2) + bfhi(u3))) +
                    ((bfhi(u4) + bfhi(u5)) + (bfhi(u6) + bfhi(u7)));
        }
        for (; k < n; ++k) {
            const unsigned u = colp[(size_t)lst[k] * 128];
            accx += bflo(u);
            accy += bfhi(u);
        }
    }
    const float cx = fminf(fmaxf(accx, 0.f), 1.f);
    const float cy = fminf(fmaxf(accy, 0.f), 1.f);
    const bool sd = (side[s] != 0);
    const int base = (isWhite == sd) ? 0 : 256;   // white -> first half iff side
    sh_o0[base + 2 * h]     = cx;
    sh_o0[base + 2 * h + 1] = cy;
    __syncthreads();

    // ---- l1: (32,512); 8 threads/output, p-staggered (bank-conflict-free) ----
    {
        const int o = tid >> 3;
        const int p = tid & 7;
        const float4* wp = (const float4*)(l1_w + (o * 512 + p * 64));
        const float4* xp = (const float4*)(sh_o0 + p * 64);
        float sum = 0.f;
#pragma unroll
        for (int i = 0; i < 16; ++i) {
            const int v = (2 * p + i) & 15;
            float4 w4 = wp[v];
            float4 x4 = xp[v];
            sum += w4.x * x4.x + w4.y * x4.y + w4.z * x4.z + w4.w * x4.w;
        }
        sum += __shfl_down(sum, 4, 8);
        sum += __shfl_down(sum, 2, 8);
        sum += __shfl_down(sum, 1, 8);
        if (p == 0) sh_o1[o] = fminf(fmaxf(sum + l1_b[o], 0.f), 1.f);
    }
    __syncthreads();

    if (tid < 32) {
        float sum = 0.f;
#pragma unroll
        for (int k = 0; k < 32; ++k) sum += l2_w[tid * 32 + k] * sh_o1[k];
        sh_o2[tid] = fminf(fmaxf(sum + l2_b[tid], 0.f), 1.f);
    }
    __syncthreads();

    if (tid < 32) {
        float p = l3_w[tid] * sh_o2[tid];
        p += __shfl_down(p, 16, 32);
        p += __shfl_down(p, 8, 32);
        p += __shfl_down(p, 4, 32);
        p += __shfl_down(p, 2, 32);
        p += __shfl_down(p, 1, 32);
        if (tid == 0) {
            const float o3 = (p + l3_b[0]) * 300.0f;
            out[s] = 1.0f / (1.0f + expf(-o3 / 200.0f));
        }
    }
}

// ---------------------------------------------------------------- fallback (f32, untransposed)
__global__ __launch_bounds__(256) void nnue_kernel(
    const float* __restrict__ white, const float* __restrict__ black,
    const int* __restrict__ side, const float* __restrict__ ftw,
    const float* __restrict__ ft_b, const float* __restrict__ l1_w,
    const float* __restrict__ l1_b, const float* __restrict__ l2_w,
    const float* __restrict__ l2_b, const float* __restrict__ l3_w,
    const float* __restrict__ l3_b, float* __restrict__ out)
{
    __shared__ int w_list[MAXF];
    __shared__ int b_list[MAXF];
    __shared__ int w_cnt, b_cnt;
    __shared__ float sh_o0[512] __attribute__((aligned(16)));
    __shared__ float sh_o1[32];
    __shared__ float sh_o2[32];
    const int s = blockIdx.x, tid = threadIdx.x;
    if (tid == 0) { w_cnt = 0; b_cnt = 0; }
    __syncthreads();
    const uint4* wrow = (const uint4*)(white + (size_t)s * NIN);
    const uint4* brow = (const uint4*)(black + (size_t)s * NIN);
#pragma unroll
    for (int i = 0; i < 12; ++i) {
        const int v = i * 256 + tid;
        uint4 u = wrow[v];
        if (u.x | u.y | u.z | u.w) {
            if (u.x) { int p = atomicAdd(&w_cnt, 1); if (p < MAXF) w_list[p] = v * 4 + 0; }
            if (u.y) { int p = atomicAdd(&w_cnt, 1); if (p < MAXF) w_list[p] = v * 4 + 1; }
            if (u.z) { int p = atomicAdd(&w_cnt, 1); if (p < MAXF) w_list[p] = v * 4 + 2; }
            if (u.w) { int p = atomicAdd(&w_cnt, 1); if (p < MAXF) w_list[p] = v * 4 + 3; }
        }
        uint4 b = brow[v];
        if (b.x | b.y | b.z | b.w) {
            if (b.x) { int p = atomicAdd(&b_cnt, 1); if (p < MAXF) b_list[p] = v * 4 + 0; }
            if (b.y) { int p = atomicAdd(&b_cnt, 1); if (p < MAXF) b_list[p] = v * 4 + 1; }
            if (b.z) { int p = atomicAdd(&b_cnt, 1); if (p < MAXF) b_list[p] = v * 4 + 2; }
            if (b.w) { int p = atomicAdd(&b_cnt, 1); if (p < MAXF) b_list[p] = v * 4 + 3; }
        }
    }
    __syncthreads();
    const int wn = min(w_cnt, MAXF), bn = min(b_cnt, MAXF);
    const float bias = ft_b[tid];
    float wacc = bias, bacc = bias;
    for (int k = 0; k < wn; ++k) wacc += ftw[(size_t)tid * NIN + w_list[k]];
    for (int k = 0; k < bn; ++k) bacc += ftw[(size_t)tid * NIN + b_list[k]];
    const float ow = fminf(fmaxf(wacc, 0.f), 1.f);
    const float ob = fminf(fmaxf(bacc, 0.f), 1.f);
    const bool sd = (side[s] != 0);
    sh_o0[tid] = sd ? ow : ob;
    sh_o0[256 + tid] = sd ? ob : ow;
    __syncthreads();
    {
        const int o = tid >> 3, p = tid & 7;
        const float4* wp = (const float4*)(l1_w + (o * 512 + p * 64));
        const float4* xp = (const float4*)(sh_o0 + p * 64);
        float sum = 0.f;
#pragma unroll
        for (int i = 0; i < 16; ++i) {
            const int v = (2 * p + i) & 15;
            float4 w4 = wp[v]; float4 x4 = xp[v];
            sum += w4.x * x4.x + w4.y * x4.y + w4.z * x4.z + w4.w * x4.w;
        }
        sum += __shfl_down(sum, 4, 8);
        sum += __shfl_down(sum, 2, 8);
        sum += __shfl_down(sum, 1, 8);
        if (p == 0) sh_o1[o] = fminf(fmaxf(sum + l1_b[o], 0.f), 1.f);
    }
    __syncthreads();
    if (tid < 32) {
        float sum = 0.f;
#pragma unroll
        for (int k = 0; k < 32; ++k) sum += l2_w[tid * 32 + k] * sh_o1[k];
        sh_o2[tid] = fminf(fmaxf(sum + l2_b[tid], 0.f), 1.f);
    }
    __syncthreads();
    if (tid < 32) {
        float p = l3_w[tid] * sh_o2[tid];
        p += __shfl_down(p, 16, 32);
        p += __shfl_down(p, 8, 32);
        p += __shfl_down(p, 4, 32);
        p += __shfl_down(p, 2, 32);
        p += __shfl_down(p, 1, 32);
        if (tid == 0) {
            const float o3 = (p + l3_b[0]) * 300.0f;
            out[s] = 1.0f / (1.0f + expf(-o3 / 200.0f));
        }
    }
}

// ---------------------------------------------------------------- launch
extern "C" void kernel_launch(void* const* d_in, const int* in_sizes, int n_in,
                              void* d_out, int out_size, void* d_ws, size_t ws_size,
                              hipStream_t stream) {
    const float* white = (const float*)d_in[0];
    const float* black = (const float*)d_in[1];
    const int*   side  = (const int*)d_in[2];
    const float* ft_w  = (const float*)d_in[3];
    const float* ft_b  = (const float*)d_in[4];
    const float* l1_w  = (const float*)d_in[5];
    const float* l1_b  = (const float*)d_in[6];
    const float* l2_w  = (const float*)d_in[7];
    const float* l2_b  = (const float*)d_in[8];
    const float* l3_w  = (const float*)d_in[9];
    const float* l3_b  = (const float*)d_in[10];
    float*       out   = (float*)d_out;

    const int B = in_sizes[2];
    const size_t t_bytes = (size_t)NIN * H0 * 2;   // bf16 ftw_t: 6.29 MB

    if (ws_size >= t_bytes) {
        unsigned short* ftw_t = (unsigned short*)d_ws;
        hipLaunchKernelGGL(transpose_ftw_bf16, dim3(NIN / 32, H0 / 32), dim3(32, 8), 0, stream,
                           ft_w, ftw_t);
        hipLaunchKernelGGL(nnue_mono, dim3(B), dim3(256), 0, stream,
                           white, black, side, (const unsigned*)ftw_t, ft_b,
                           l1_w, l1_b, l2_w, l2_b, l3_w, l3_b, out);
    } else {
        hipLaunchKernelGGL(nnue_kernel, dim3(B), dim3(256), 0, stream,
                           white, black, side, ft_w, ft_b, l1_w, l1_b, l2_w, l2_b,
                           l3_w, l3_b, out);
    }
}